// Round 3
// baseline (2177.588 us; speedup 1.0000x reference)
//
#include <hip/hip_runtime.h>
#include <stdint.h>

#define N_SAMP  2000000
#define NSTEP   32
#define INV_N   (1.0/2000000.0)

#define OUT_BE  2000000
#define OUT_BP  2000204
#define OUT_ETA 2000408
#define OUT_TH  2000606
#define OUT_DH  2000804

// ---------------- threefry2x32 core cipher, bit-exact vs JAX ----------------
__host__ __device__ inline void threefry2x32(uint32_t k0, uint32_t k1,
                                             uint32_t c0, uint32_t c1,
                                             uint32_t* o0, uint32_t* o1) {
  uint32_t ks2 = k0 ^ k1 ^ 0x1BD11BDAu;
  uint32_t x0 = c0 + k0;
  uint32_t x1 = c1 + k1;
#define TF_ROT(x, d) (((x) << (d)) | ((x) >> (32 - (d))))
#define TF_R(a,b,c,d, ka, kb, inc) \
  x0 += x1; x1 = TF_ROT(x1, a); x1 ^= x0; \
  x0 += x1; x1 = TF_ROT(x1, b); x1 ^= x0; \
  x0 += x1; x1 = TF_ROT(x1, c); x1 ^= x0; \
  x0 += x1; x1 = TF_ROT(x1, d); x1 ^= x0; \
  x0 += (ka); x1 += (kb) + (inc);
  TF_R(13,15,26,6,  k1,  ks2, 1u)
  TF_R(17,29,16,24, ks2, k0,  2u)
  TF_R(13,15,26,6,  k0,  k1,  3u)
  TF_R(17,29,16,24, k1,  ks2, 4u)
  TF_R(13,15,26,6,  ks2, k0,  5u)
#undef TF_R
#undef TF_ROT
  *o0 = x0; *o1 = x1;
}

// bits -> N(0,1), matching jax.random.normal f32 path (uniform map + XLA erfinv)
__device__ inline float bits_to_normal(uint32_t bits) {
  float f = __uint_as_float((bits >> 9) | 0x3f800000u) - 1.0f;   // [0,1)
  const float lo = -0.99999994f;                                  // nextafter(-1,0)
  float u = f * 2.0f + lo;                                        // (hi-lo) == 2.0f exactly
  u = fmaxf(lo, u);
  float w = -log1pf(-u * u);
  float p;
  if (w < 5.0f) {
    w = w - 2.5f;
    p = 2.81022636e-08f;
    p = fmaf(p, w, 3.43273939e-07f);
    p = fmaf(p, w, -3.5233877e-06f);
    p = fmaf(p, w, -4.39150654e-06f);
    p = fmaf(p, w, 0.00021858087f);
    p = fmaf(p, w, -0.00125372503f);
    p = fmaf(p, w, -0.00417768164f);
    p = fmaf(p, w, 0.246640727f);
    p = fmaf(p, w, 1.50140941f);
  } else {
    w = sqrtf(w) - 3.0f;
    p = -0.000200214257f;
    p = fmaf(p, w, 0.000100950558f);
    p = fmaf(p, w, 0.00134934322f);
    p = fmaf(p, w, -0.00367342844f);
    p = fmaf(p, w, 0.00573950773f);
    p = fmaf(p, w, -0.0076224613f);
    p = fmaf(p, w, 0.00943887047f);
    p = fmaf(p, w, 1.00167406f);
    p = fmaf(p, w, 2.83297682f);
  }
  return __uint_as_float(0x3FB504F3u) * (p * u);  // sqrt(2) f32 * erfinv(u)
}

// 6x6 solve, Gaussian elimination without pivoting (G is SPD), result in b
__device__ inline void solve6(double G[6][6], double b[6]) {
#pragma unroll
  for (int c = 0; c < 6; c++) {
    double inv = 1.0 / G[c][c];
#pragma unroll
    for (int r = c + 1; r < 6; r++) {
      double fct = G[r][c] * inv;
#pragma unroll
      for (int cc = c + 1; cc < 6; cc++) G[r][cc] -= fct * G[c][cc];
      b[r] -= fct * b[c];
    }
  }
#pragma unroll
  for (int r = 5; r >= 0; r--) {
    double s = b[r];
#pragma unroll
    for (int cc = r + 1; cc < 6; cc++) s -= G[r][cc] * b[cc];
    b[r] = s / G[r][r];
  }
}

// block reduce NQ doubles (blockDim==256) then one atomic per quantity.
// slot quantities use 64B stride (q*8 doubles).
template <int NQ>
__device__ inline void block_reduce_atomic(double* acc, double* slot) {
  __shared__ double sm[4][NQ];
  int lane = threadIdx.x & 63, wid = threadIdx.x >> 6;
#pragma unroll
  for (int q = 0; q < NQ; q++) {
    double v = acc[q];
    for (int off = 32; off > 0; off >>= 1) v += __shfl_down(v, off, 64);
    if (lane == 0) sm[wid][q] = v;
  }
  __syncthreads();
  if (threadIdx.x < NQ) {
    double s = sm[0][threadIdx.x] + sm[1][threadIdx.x] + sm[2][threadIdx.x] + sm[3][threadIdx.x];
    atomicAdd(&slot[threadIdx.x * 8], s);
  }
}

__device__ inline void buildG(const double* __restrict__ Sslot, double G[6][6]) {
  double S[11];
  S[0] = 1.0;
#pragma unroll
  for (int m = 1; m <= 10; m++) S[m] = Sslot[(m - 1) * 8] * INV_N;
#pragma unroll
  for (int i = 0; i < 6; i++)
#pragma unroll
    for (int j = 0; j < 6; j++) G[i][j] = (double)((i + 1) * (j + 1)) * S[i + j];
#pragma unroll
  for (int i = 0; i < 6; i++) G[i][i] *= 1.001;   // REG=(1e-3,0,0): d>=0 always
}

// ---------------- setup reduction: 27 joint moments of (x0,x1) + 10 moments of x_k
__global__ __launch_bounds__(256) void k_reduce0(const float* __restrict__ x1g,
                                                 const float* __restrict__ x0g,
                                                 const float* __restrict__ xkg,
                                                 double* __restrict__ slot) {
  double acc[37];
#pragma unroll
  for (int q = 0; q < 37; q++) acc[q] = 0.0;
  int stride = gridDim.x * blockDim.x;
  for (int i = blockIdx.x * blockDim.x + threadIdx.x; i < N_SAMP; i += stride) {
    float a0 = x0g[i], a1 = x1g[i], xk = xkg[i];
    float p0[7], p1[7];
    p0[0] = 1.f; p1[0] = 1.f;
#pragma unroll
    for (int m = 0; m < 6; m++) { p0[m + 1] = p0[m] * a0; p1[m + 1] = p1[m] * a1; }
    int q = 0;
#pragma unroll
    for (int s = 1; s <= 6; s++)
#pragma unroll
      for (int a = 0; a <= s; a++) acc[q++] += (double)(p0[a] * p1[s - a]);
    float xp = xk;
    acc[27] += (double)xp;
#pragma unroll
    for (int m = 1; m < 10; m++) { xp *= xk; acc[27 + m] += (double)xp; }
  }
  block_reduce_atomic<37>(acc, slot);
}

// ---------------- per-step scalars from joint moments (32 threads)
__global__ void k_scalars(const float* __restrict__ t, const double* __restrict__ D,
                          float* __restrict__ F) {
  int k = threadIdx.x;
  if (k >= NSTEP) return;
  double M[7][7];
  M[0][0] = 1.0;
  for (int s = 1; s <= 6; s++)
    for (int a = 0; a <= s; a++)
      M[a][s - a] = D[(((s + 2) * (s - 1)) / 2 + a) * 8] * INV_N;
  float tk = t[k], tk1 = t[k + 1];
  float h = tk1 - tk;
  float ns = sqrtf(2.0f * h) * 0.5f;                  // sqrt(2h)*SIGMA
  const float PI_F = 3.14159274f;                     // float(np.pi)
  float arg = (PI_F * tk) * 0.5f;
  float arg1 = (PI_F * tk1) * 0.5f;
  double a = (double)cosf(arg), b = (double)sinf(arg);
  double a1 = (double)cosf(arg1), b1 = (double)sinf(arg1);
  const double C2 = (double)1.57079637f;              // f32(pi/2) as the reference uses
  const double B[7][7] = {
      {1, 0, 0, 0, 0, 0, 0},  {1, 1, 0, 0, 0, 0, 0},   {1, 2, 1, 0, 0, 0, 0},
      {1, 3, 3, 1, 0, 0, 0},  {1, 4, 6, 4, 1, 0, 0},   {1, 5, 10, 10, 5, 1, 0},
      {1, 6, 15, 20, 15, 6, 1}};
  double pa[7], pb[7], pa1[7], pb1[7];
  pa[0] = pb[0] = pa1[0] = pb1[0] = 1.0;
  for (int i = 1; i < 7; i++) {
    pa[i] = pa[i - 1] * a;  pb[i] = pb[i - 1] * b;
    pa1[i] = pa1[i - 1] * a1; pb1[i] = pb1[i - 1] * b1;
  }
  float* Fk = F + k * 20;
  Fk[0] = h; Fk[1] = ns;
  for (int p = 1; p <= 6; p++) {
    double s_rhs = 0, s_bpe = 0, s_dt = 0;
    for (int j = 0; j < p; j++) {
      double term = -b * M[j + 1][p - 1 - j] + a * M[j][p - j];   // Idot_k part
      s_rhs += B[p - 1][j] * pa[j]  * pb[p - 1 - j]  * term;      // grad at I_k
      s_dt  += B[p - 1][j] * pa1[j] * pb1[p - 1 - j] * term;      // grad at I_{k+1}
    }
    for (int j = 0; j <= p; j++) s_bpe += B[p][j] * pa1[j] * pb1[p - j] * M[j][p - j];
    Fk[2 + p - 1]  = (float)((double)p * C2 * s_rhs);
    Fk[8 + p - 1]  = (float)s_bpe;
    Fk[14 + p - 1] = (float)((double)p * C2 * s_dt);
  }
}

// ---------------- predictor: y = x + h*gp(x)@eta + noise; accumulate S(y) 1..10
// Noise matches jax_threefry_partitionable=True (JAX >= 0.4.36 default):
// per-element 64-bit counter (0, i), bits = out0 ^ out1.
// NOTE: xin and yout may alias (in-place update of d_out) — no __restrict__.
__global__ __launch_bounds__(256) void k_pred(const float* xin,
                                              float* yout,
                                              const double* __restrict__ Sslot,
                                              const float* __restrict__ Fk,
                                              double* __restrict__ SyOut,
                                              uint32_t kk0, uint32_t kk1) {
  double G[6][6];
  buildG(Sslot, G);
  double rhs[6];
#pragma unroll
  for (int i = 0; i < 6; i++) rhs[i] = (double)Fk[2 + i];
  solve6(G, rhs);
  float h = Fk[0], ns = Fk[1];
  float c0 = (float)rhs[0],      c1 = 2.f * (float)rhs[1], c2 = 3.f * (float)rhs[2];
  float c3 = 4.f * (float)rhs[3], c4 = 5.f * (float)rhs[4], c5 = 6.f * (float)rhs[5];
  double acc[10];
#pragma unroll
  for (int q = 0; q < 10; q++) acc[q] = 0.0;
  int stride = gridDim.x * blockDim.x;
  for (int i = blockIdx.x * blockDim.x + threadIdx.x; i < N_SAMP; i += stride) {
    uint32_t o0, o1;
    threefry2x32(kk0, kk1, 0u, (uint32_t)i, &o0, &o1);
    float nz = bits_to_normal(o0 ^ o1);
    float x = xin[i];
    float d = c0 + x * (c1 + x * (c2 + x * (c3 + x * (c4 + x * c5))));
    float y = x + h * d + ns * nz;
    yout[i] = y;
    float pw = y;
    acc[0] += (double)pw;
#pragma unroll
    for (int m = 1; m < 10; m++) { pw *= y; acc[m] += (double)pw; }
  }
  block_reduce_atomic<10>(acc, SyOut);
}

// ---------------- corrector: x = y + gp(y)@theta; accumulate S(x) 1..10
// NOTE: yin and xout alias (in-place update of d_out) — no __restrict__.
__global__ __launch_bounds__(256) void k_corr(const float* yin,
                                              float* xout,
                                              const double* __restrict__ Syslot,
                                              const float* __restrict__ Fk,
                                              double* __restrict__ SxOut) {
  double G[6][6];
  buildG(Syslot, G);
  double rhs[6];
#pragma unroll
  for (int i = 0; i < 6; i++)
    rhs[i] = (double)Fk[8 + i] - Syslot[i * 8] * INV_N;   // bpe - mean(moments(y))
  solve6(G, rhs);
  float c0 = (float)rhs[0],      c1 = 2.f * (float)rhs[1], c2 = 3.f * (float)rhs[2];
  float c3 = 4.f * (float)rhs[3], c4 = 5.f * (float)rhs[4], c5 = 6.f * (float)rhs[5];
  double acc[10];
#pragma unroll
  for (int q = 0; q < 10; q++) acc[q] = 0.0;
  int stride = gridDim.x * blockDim.x;
  for (int i = blockIdx.x * blockDim.x + threadIdx.x; i < N_SAMP; i += stride) {
    float y = yin[i];
    float corr = c0 + y * (c1 + y * (c2 + y * (c3 + y * (c4 + y * c5))));
    float x = y + corr;
    xout[i] = x;
    float px = x;
    acc[0] += (double)px;
#pragma unroll
    for (int m = 1; m < 10; m++) { px *= x; acc[m] += (double)px; }
  }
  block_reduce_atomic<10>(acc, SxOut);
}

// ---------------- finalize: recompute eta/theta per step, write all small outputs
__global__ void k_final(const double* __restrict__ D, const float* __restrict__ F,
                        float* __restrict__ out) {
  int k = threadIdx.x;
  const double* D_SXK = D + 27 * 8;
  const double* D_SY = D + 296;
  const double* D_SX = D + 2856;
  if (k < NSTEP) {
    const float* Fk = F + k * 20;
    // eta_k
    {
      const double* Ss = (k == 0) ? D_SXK : (D_SX + (k - 1) * 80);
      double G[6][6];
      buildG(Ss, G);
      double rhs[6];
      for (int i = 0; i < 6; i++) rhs[i] = (double)Fk[2 + i];
      solve6(G, rhs);
      for (int i = 0; i < 6; i++) {
        float v = (float)rhs[i];
        out[OUT_ETA + k * 6 + i] = v;
        if (k == NSTEP - 1) out[OUT_ETA + NSTEP * 6 + i] = v;
      }
    }
    // theta_k, dH_k
    {
      const double* Sy = D_SY + k * 80;
      double G[6][6];
      buildG(Sy, G);
      double rhs[6];
      for (int i = 0; i < 6; i++) rhs[i] = (double)Fk[8 + i] - Sy[i * 8] * INV_N;
      solve6(G, rhs);
      float h = Fk[0];
      float denom = h * 0.25f;   // h * SIGMA^2
      float dH = 0.f;
      for (int i = 0; i < 6; i++) {
        float th = (float)rhs[i] / denom;
        out[OUT_TH + k * 6 + i] = th;
        if (k == NSTEP - 1) out[OUT_TH + NSTEP * 6 + i] = th;
        dH += th * Fk[14 + i];
      }
      dH = -dH;
      out[OUT_DH + k] = dH;
      if (k == NSTEP - 1) out[OUT_DH + NSTEP] = dH;
    }
    // barphi_e row k+1 ; barphi_p row k+1
    {
      const double* Sx = D_SX + k * 80;
      for (int i = 0; i < 6; i++) {
        float be = Fk[8 + i];
        float bp = (float)(Sx[i * 8] * INV_N);
        out[OUT_BE + (k + 1) * 6 + i] = be;
        out[OUT_BP + (k + 1) * 6 + i] = bp;
        if (k == NSTEP - 1) {
          out[OUT_BE + (NSTEP + 1) * 6 + i] = be;
          out[OUT_BP + (NSTEP + 1) * 6 + i] = bp;
        }
      }
    }
  } else if (k == NSTEP) {
    // row 0: moments of x_0 (from joint moments M_{p,0}) and of x_k
    for (int p = 1; p <= 6; p++) {
      int idx = ((p + 2) * (p - 1)) / 2 + p;  // M_{a=p,b=0}
      out[OUT_BE + (p - 1)] = (float)(D[idx * 8] * INV_N);
      out[OUT_BP + (p - 1)] = (float)(D_SXK[(p - 1) * 8] * INV_N);
    }
  }
}

extern "C" void kernel_launch(void* const* d_in, const int* in_sizes, int n_in,
                              void* d_out, int out_size, void* d_ws, size_t ws_size,
                              hipStream_t stream) {
  const float* x1 = (const float*)d_in[0];
  const float* x0 = (const float*)d_in[1];
  const float* xk = (const float*)d_in[2];
  const float* t  = (const float*)d_in[3];
  float* out = (float*)d_out;

  // All scratch at the FRONT of ws: 5416 doubles + 640 floats = 45888 bytes.
  // State x/y lives in-place in d_out[0..2M) — no large ws buffer needed.
  double* D = (double*)d_ws;
  double* D_SXK = D + 27 * 8;      // 10 quantities * stride 8
  double* D_SY  = D + 296;         // 32 * (10*8)
  double* D_SX  = D + 2856;        // 32 * (10*8)
  float*  F     = (float*)(D + 5416);  // 32 * 20 floats

  hipMemsetAsync(D, 0, (size_t)(5416 * 8 + 640 * 4), stream);

  dim3 blk(256), grd(1024);
  k_reduce0<<<grd, blk, 0, stream>>>(x1, x0, xk, D);
  k_scalars<<<1, 64, 0, stream>>>(t, D, F);

  for (int k = 0; k < NSTEP; k++) {
    uint32_t kk0, kk1;
    threefry2x32(0u, 42u, 0u, (uint32_t)k, &kk0, &kk1);  // fold_in(key(42), k)
    const float* xin = (k == 0) ? xk : out;
    const double* Ss = (k == 0) ? D_SXK : (D_SX + (k - 1) * 80);
    k_pred<<<grd, blk, 0, stream>>>(xin, out, Ss, F + k * 20, D_SY + k * 80, kk0, kk1);
    k_corr<<<grd, blk, 0, stream>>>(out, out, D_SY + k * 80, F + k * 20, D_SX + k * 80);
  }
  k_final<<<1, 64, 0, stream>>>(D, F, out);
}